// Round 2
// baseline (1538.575 us; speedup 1.0000x reference)
//
#include <hip/hip_runtime.h>
#include <hip/hip_cooperative_groups.h>

namespace cg = cooperative_groups;

#define BB   16    // batch
#define NW   32    // WORDS (output capsules)
#define DIMM 256   // DIM
#define DH   32    // DIM_HEAD
#define NI   256   // INNER
#define NJ   256   // J = WORDS*HEADS (input capsules)
#define JP   4     // j's per route/uhat unit
#define JG   (NJ / JP)   // 64 j-groups
#define GRID 1024  // 4 blocks/CU * 256 CU, guaranteed co-resident under launch_bounds(256,4)

// ---------------- fused persistent kernel ----------------
// Phases separated by grid.sync():
//  P0 proj_in -> P1 uhat(+iter0 partials) -> P2 reduce(v0) -> P3 route1 ->
//  P4 reduce(v1) -> P5 route2 -> P6 reduce(v2) -> P7 proj_out

__device__ __forceinline__ void phase_reduce(const float* __restrict__ part,
                                             float* __restrict__ v, float scale,
                                             int nb, int bid, int tid, float* sm) {
    for (int unit = bid; unit < BB * NW; unit += nb) {
        int b = unit >> 5, i = unit & 31;
        int lane = tid & 63, wave = tid >> 6;
        float acc = 0.f;
#pragma unroll 16
        for (int g = 0; g < JG; ++g)
            acc += part[(((size_t)b * JG + g) * NW + i) * NI + tid];
        acc *= scale;
        float p = acc * acc;
#pragma unroll
        for (int off = 32; off >= 1; off >>= 1) p += __shfl_down(p, off);
        __syncthreads();                 // guard sm reuse from previous phase/unit
        if (lane == 0) sm[wave] = p;
        __syncthreads();
        float n2 = sm[0] + sm[1] + sm[2] + sm[3];
        float n = sqrtf(n2);
        float f = n / (1.0f + n2);
        v[((size_t)b * NW + i) * NI + tid] = f * acc;
    }
}

__device__ __forceinline__ void phase_route(const float* __restrict__ u,
                                            const float* __restrict__ v,
                                            float* __restrict__ b_log,
                                            float* __restrict__ part, int accflag,
                                            int nb, int bid, int tid, float* sm) {
    for (int unit = bid; unit < BB * JG; unit += nb) {
        int b = unit / JG, jg = unit % JG;
        int i = tid >> 3, h = tid & 7;
        // v fragment: v[b, i, h*32 .. h*32+31]
        float vr[32];
        {
            const float4* vp = (const float4*)(v + ((size_t)b * NW + i) * NI + h * 32);
#pragma unroll
            for (int q = 0; q < 8; ++q) ((float4*)vr)[q] = vp[q];
        }
        float s_acc[32];
#pragma unroll
        for (int k = 0; k < 32; ++k) s_acc[k] = 0.f;

        for (int jj = 0; jj < JP; ++jj) {
            int j = jg * JP + jj;
            float ur[32];
            {
                const float4* up = (const float4*)(u + (((size_t)b * NJ + j) * NW + i) * NI + h * 32);
#pragma unroll
                for (int q = 0; q < 8; ++q) ((float4*)ur)[q] = up[q];
            }
            float p = 0.f;
#pragma unroll
            for (int k = 0; k < 32; ++k) p += ur[k] * vr[k];
            p += __shfl_xor(p, 1);
            p += __shfl_xor(p, 2);
            p += __shfl_xor(p, 4);
            __syncthreads();             // previous jj's sm readers are done
            if (h == 0) {
                size_t bidx = ((size_t)b * NJ + j) * NW + i;
                float bta = p;
                if (accflag) bta += b_log[bidx];
                b_log[bidx] = bta;
                sm[i] = bta;
            }
            __syncthreads();
            // 8-lane-group parallel softmax over the 32 output capsules
            float r0 = sm[h * 4 + 0];
            float r1 = sm[h * 4 + 1];
            float r2 = sm[h * 4 + 2];
            float r3 = sm[h * 4 + 3];
            float m = fmaxf(fmaxf(r0, r1), fmaxf(r2, r3));
            m = fmaxf(m, __shfl_xor(m, 1));
            m = fmaxf(m, __shfl_xor(m, 2));
            m = fmaxf(m, __shfl_xor(m, 4));
            float ss = __expf(r0 - m) + __expf(r1 - m) + __expf(r2 - m) + __expf(r3 - m);
            ss += __shfl_xor(ss, 1);
            ss += __shfl_xor(ss, 2);
            ss += __shfl_xor(ss, 4);
            float c = __expf(sm[i] - m) / ss;
#pragma unroll
            for (int k = 0; k < 32; ++k) s_acc[k] += c * ur[k];
        }
        float4* pp = (float4*)(part + (((size_t)b * JG + jg) * NW + i) * NI + h * 32);
#pragma unroll
        for (int q = 0; q < 8; ++q) pp[q] = ((float4*)s_acc)[q];
    }
}

__global__ void __launch_bounds__(256, 4)
k_fused(const float* __restrict__ x, const float* __restrict__ W,
        const float* __restrict__ bias, const float* __restrict__ Wi,
        const float* __restrict__ bi, const float* __restrict__ Wo,
        const float* __restrict__ bo, float* __restrict__ out,
        float* __restrict__ xh, float* __restrict__ u,
        float* __restrict__ part, float* __restrict__ b_log,
        float* __restrict__ v) {
    cg::grid_group gg = cg::this_grid();
    const int bid = blockIdx.x;
    const int tid = threadIdx.x;
    const int nb = gridDim.x;
    __shared__ float sm[JP * BB * DH];   // 2048 floats = 8 KB, reused by all phases

    // ---- P0: xh = x @ Wi^T + bi ----
    for (int row = bid; row < BB * NW; row += nb) {
        __syncthreads();
        sm[tid] = x[(size_t)row * DIMM + tid];
        __syncthreads();
        const float4* wi  = (const float4*)(Wi + (size_t)tid * DIMM);
        const float4* xr4 = (const float4*)sm;
        float acc = bi[tid];
#pragma unroll 8
        for (int m = 0; m < DIMM / 4; ++m) {
            float4 w = wi[m]; float4 xv = xr4[m];
            acc += w.x * xv.x + w.y * xv.y + w.z * xv.z + w.w * xv.w;
        }
        xh[(size_t)row * DIMM + tid] = acc;
    }
    gg.sync();

    // ---- P1: u_hat + iter-0 uniform partial sums ----
    for (int unit = bid; unit < JG * NW; unit += nb) {
        int jg = unit >> 5;
        int i  = unit & 31;
        int e  = tid;
        __syncthreads();
        // stage xh for this unit's 4 j's, all b: [jj][b][d] = 2048 floats
        for (int t = tid; t < JP * BB * DH; t += 256) {
            int jj = t >> 9;
            int rem = t & 511;
            int b = rem >> 5, d = rem & 31;
            sm[t] = xh[((size_t)b * NJ + jg * JP + jj) * DH + d];
        }
        __syncthreads();
        float acc0[BB];
#pragma unroll
        for (int b = 0; b < BB; ++b) acc0[b] = 0.f;
        for (int jj = 0; jj < JP; ++jj) {
            int j = jg * JP + jj;
            const float4* wp = (const float4*)(W + (((size_t)j * NW + i) * NI + e) * DH);
            float4 w4[8];
#pragma unroll
            for (int q = 0; q < 8; ++q) w4[q] = wp[q];
            const float* w = (const float*)w4;
            float bv = bias[((size_t)j * NW + i) * NI + e];
            const float* xs = sm + jj * (BB * DH);
#pragma unroll
            for (int b = 0; b < BB; ++b) {
                float a = bv;
#pragma unroll
                for (int d = 0; d < DH; ++d) a += w[d] * xs[b * 32 + d];
                u[(((size_t)b * NJ + j) * NW + i) * NI + e] = a;
                acc0[b] += a;
            }
        }
#pragma unroll
        for (int b = 0; b < BB; ++b)
            part[(((size_t)b * JG + jg) * NW + i) * NI + e] = acc0[b];
    }
    gg.sync();

    phase_reduce(part, v, 1.0f / NW, nb, bid, tid, sm);   // v0
    gg.sync();
    phase_route(u, v, b_log, part, 0, nb, bid, tid, sm);  // iter 1
    gg.sync();
    phase_reduce(part, v, 1.0f, nb, bid, tid, sm);        // v1
    gg.sync();
    phase_route(u, v, b_log, part, 1, nb, bid, tid, sm);  // iter 2
    gg.sync();
    phase_reduce(part, v, 1.0f, nb, bid, tid, sm);        // v2
    gg.sync();

    // ---- P7: out = v @ Wo^T + bo ----
    for (int row = bid; row < BB * NW; row += nb) {
        __syncthreads();
        sm[tid] = v[(size_t)row * NI + tid];
        __syncthreads();
        const float4* wo  = (const float4*)(Wo + (size_t)tid * NI);
        const float4* vr4 = (const float4*)sm;
        float acc = bo[tid];
#pragma unroll 8
        for (int m = 0; m < NI / 4; ++m) {
            float4 w = wo[m]; float4 xv = vr4[m];
            acc += w.x * xv.x + w.y * xv.y + w.z * xv.z + w.w * xv.w;
        }
        out[(size_t)row * DIMM + tid] = acc;
    }
}

// ---------------- fallback (non-cooperative) kernels: round-1 path ----------------

__global__ void k_proj_in(const float* __restrict__ x, const float* __restrict__ Wi,
                          const float* __restrict__ bi, float* __restrict__ xh) {
    int row = blockIdx.x;
    int k = threadIdx.x;
    __shared__ float xr[DIMM];
    xr[k] = x[(size_t)row * DIMM + k];
    __syncthreads();
    const float4* wi  = (const float4*)(Wi + (size_t)k * DIMM);
    const float4* xr4 = (const float4*)xr;
    float acc = bi[k];
#pragma unroll 8
    for (int m = 0; m < DIMM / 4; ++m) {
        float4 w = wi[m]; float4 xv = xr4[m];
        acc += w.x * xv.x + w.y * xv.y + w.z * xv.z + w.w * xv.w;
    }
    xh[(size_t)row * DIMM + k] = acc;
}

__global__ void k_uhat(const float* __restrict__ W, const float* __restrict__ bias,
                       const float* __restrict__ xh, float* __restrict__ u,
                       float* __restrict__ part) {
    int jg = blockIdx.x >> 5;
    int i  = blockIdx.x & 31;
    int e  = threadIdx.x;
    __shared__ float xs[JP * BB * DH];
    for (int t = threadIdx.x; t < JP * BB * DH; t += 256) {
        int jj = t >> 9;
        int rem = t & 511;
        int b = rem >> 5, d = rem & 31;
        xs[t] = xh[((size_t)b * NJ + jg * JP + jj) * DH + d];
    }
    __syncthreads();
    float acc0[BB];
#pragma unroll
    for (int b = 0; b < BB; ++b) acc0[b] = 0.f;
    for (int jj = 0; jj < JP; ++jj) {
        int j = jg * JP + jj;
        const float4* wp = (const float4*)(W + (((size_t)j * NW + i) * NI + e) * DH);
        float4 w4[8];
#pragma unroll
        for (int q = 0; q < 8; ++q) w4[q] = wp[q];
        const float* w = (const float*)w4;
        float bv = bias[((size_t)j * NW + i) * NI + e];
        const float* xp = xs + jj * (BB * DH);
#pragma unroll
        for (int b = 0; b < BB; ++b) {
            float a = bv;
#pragma unroll
            for (int d = 0; d < DH; ++d) a += w[d] * xp[b * 32 + d];
            u[(((size_t)b * NJ + j) * NW + i) * NI + e] = a;
            acc0[b] += a;
        }
    }
#pragma unroll
    for (int b = 0; b < BB; ++b)
        part[(((size_t)b * JG + jg) * NW + i) * NI + e] = acc0[b];
}

__global__ void __launch_bounds__(256, 4)
k_route(const float* __restrict__ u, const float* __restrict__ v,
        float* __restrict__ b_log, float* __restrict__ part, int accflag) {
    __shared__ float sm[NW];
    int b  = blockIdx.x / JG;
    int jg = blockIdx.x % JG;
    int t  = threadIdx.x;
    int i  = t >> 3;
    int h  = t & 7;
    float vr[32];
    {
        const float4* vp = (const float4*)(v + ((size_t)b * NW + i) * NI + h * 32);
#pragma unroll
        for (int q = 0; q < 8; ++q) ((float4*)vr)[q] = vp[q];
    }
    float s_acc[32];
#pragma unroll
    for (int k = 0; k < 32; ++k) s_acc[k] = 0.f;
    for (int jj = 0; jj < JP; ++jj) {
        int j = jg * JP + jj;
        float ur[32];
        {
            const float4* up = (const float4*)(u + (((size_t)b * NJ + j) * NW + i) * NI + h * 32);
#pragma unroll
            for (int q = 0; q < 8; ++q) ((float4*)ur)[q] = up[q];
        }
        float p = 0.f;
#pragma unroll
        for (int k = 0; k < 32; ++k) p += ur[k] * vr[k];
        p += __shfl_xor(p, 1);
        p += __shfl_xor(p, 2);
        p += __shfl_xor(p, 4);
        __syncthreads();
        if (h == 0) {
            size_t bidx = ((size_t)b * NJ + j) * NW + i;
            float bta = p;
            if (accflag) bta += b_log[bidx];
            b_log[bidx] = bta;
            sm[i] = bta;
        }
        __syncthreads();
        float r0 = sm[h * 4 + 0];
        float r1 = sm[h * 4 + 1];
        float r2 = sm[h * 4 + 2];
        float r3 = sm[h * 4 + 3];
        float m = fmaxf(fmaxf(r0, r1), fmaxf(r2, r3));
        m = fmaxf(m, __shfl_xor(m, 1));
        m = fmaxf(m, __shfl_xor(m, 2));
        m = fmaxf(m, __shfl_xor(m, 4));
        float ss = __expf(r0 - m) + __expf(r1 - m) + __expf(r2 - m) + __expf(r3 - m);
        ss += __shfl_xor(ss, 1);
        ss += __shfl_xor(ss, 2);
        ss += __shfl_xor(ss, 4);
        float c = __expf(sm[i] - m) / ss;
#pragma unroll
        for (int k = 0; k < 32; ++k) s_acc[k] += c * ur[k];
    }
    float4* pp = (float4*)(part + (((size_t)b * JG + jg) * NW + i) * NI + h * 32);
#pragma unroll
    for (int q = 0; q < 8; ++q) pp[q] = ((float4*)s_acc)[q];
}

__global__ void k_reduce(const float* __restrict__ part, float* __restrict__ v,
                         float scale) {
    int b = blockIdx.x >> 5;
    int i = blockIdx.x & 31;
    int tid = threadIdx.x;
    int lane = tid & 63, wave = tid >> 6;
    float acc = 0.f;
#pragma unroll 16
    for (int g = 0; g < JG; ++g)
        acc += part[(((size_t)b * JG + g) * NW + i) * NI + tid];
    acc *= scale;
    __shared__ float red[4];
    float p = acc * acc;
#pragma unroll
    for (int off = 32; off >= 1; off >>= 1) p += __shfl_down(p, off);
    if (lane == 0) red[wave] = p;
    __syncthreads();
    float n2 = red[0] + red[1] + red[2] + red[3];
    float n = sqrtf(n2);
    float f = n / (1.0f + n2);
    v[((size_t)b * NW + i) * NI + tid] = f * acc;
}

__global__ void k_proj_out(const float* __restrict__ v, const float* __restrict__ Wo,
                           const float* __restrict__ bo, float* __restrict__ out) {
    int row = blockIdx.x;
    int k = threadIdx.x;
    __shared__ float vr[NI];
    vr[k] = v[(size_t)row * NI + k];
    __syncthreads();
    const float4* wo  = (const float4*)(Wo + (size_t)k * NI);
    const float4* vr4 = (const float4*)vr;
    float acc = bo[k];
#pragma unroll 8
    for (int m = 0; m < NI / 4; ++m) {
        float4 w = wo[m]; float4 xv = vr4[m];
        acc += w.x * xv.x + w.y * xv.y + w.z * xv.z + w.w * xv.w;
    }
    out[(size_t)row * DIMM + k] = acc;
}

extern "C" void kernel_launch(void* const* d_in, const int* in_sizes, int n_in,
                              void* d_out, int out_size, void* d_ws, size_t ws_size,
                              hipStream_t stream) {
    const float* x    = (const float*)d_in[0];
    const float* W    = (const float*)d_in[1];
    const float* bias = (const float*)d_in[2];
    const float* Wi   = (const float*)d_in[3];
    const float* bi   = (const float*)d_in[4];
    const float* Wo   = (const float*)d_in[5];
    const float* bo   = (const float*)d_in[6];
    float* out = (float*)d_out;

    float* ws    = (float*)d_ws;
    float* xh    = ws;                      // 131072 floats
    float* u     = ws + 131072;             // 33554432 floats (134 MB)
    float* part  = u + 33554432;            // 8388608 floats (32 MB)
    float* b_log = part + 8388608;          // 131072
    float* v     = b_log + 131072;          // 131072

    void* args[] = {(void*)&x, (void*)&W, (void*)&bias, (void*)&Wi, (void*)&bi,
                    (void*)&Wo, (void*)&bo, (void*)&out, (void*)&xh, (void*)&u,
                    (void*)&part, (void*)&b_log, (void*)&v};
    hipError_t err = hipLaunchCooperativeKernel((const void*)k_fused, dim3(GRID),
                                                dim3(256), args, 0, stream);
    if (err != hipSuccess) {
        // fallback: non-cooperative multi-kernel path (round-1 behavior)
        k_proj_in<<<dim3(BB * NW), dim3(256), 0, stream>>>(x, Wi, bi, xh);
        k_uhat<<<dim3(JG * NW), dim3(256), 0, stream>>>(W, bias, xh, u, part);
        k_reduce<<<dim3(BB * NW), dim3(256), 0, stream>>>(part, v, 1.0f / NW);
        k_route<<<dim3(BB * JG), dim3(256), 0, stream>>>(u, v, b_log, part, 0);
        k_reduce<<<dim3(BB * NW), dim3(256), 0, stream>>>(part, v, 1.0f);
        k_route<<<dim3(BB * JG), dim3(256), 0, stream>>>(u, v, b_log, part, 1);
        k_reduce<<<dim3(BB * NW), dim3(256), 0, stream>>>(part, v, 1.0f);
        k_proj_out<<<dim3(BB * NW), dim3(256), 0, stream>>>(v, Wo, bo, out);
    }
}

// Round 3
// 893.932 us; speedup vs baseline: 1.7211x; 1.7211x over previous
//
#include <hip/hip_runtime.h>

#define BB   16    // batch
#define NW   32    // WORDS (output capsules)
#define DIMM 256   // DIM
#define DH   32    // DIM_HEAD
#define NI   256   // INNER
#define NJ   256   // J = WORDS*HEADS (input capsules)
#define JPU  8     // j's per uhat block
#define JGU  (NJ / JPU)   // 32
#define JPR  8     // j's per route block
#define JGR  (NJ / JPR)   // 32

// xi = x @ Wi^T + bi -> stored as xh [B, NJ, DH]; also zeroes s0/s1/s2
// (the atomic accumulation targets) so no separate memset dispatch is needed.
// grid: 512 blocks (b*NW+n); 512*256 threads == 131072 == elements per s buffer.
__global__ void k_proj_in(const float* __restrict__ x, const float* __restrict__ Wi,
                          const float* __restrict__ bi, float* __restrict__ xh,
                          float* __restrict__ s0, float* __restrict__ s1,
                          float* __restrict__ s2) {
    int row = blockIdx.x;          // b*NW + n  (512 rows)
    int k = threadIdx.x;           // 0..255
    size_t idx = (size_t)row * 256 + k;
    s0[idx] = 0.f; s1[idx] = 0.f; s2[idx] = 0.f;
    __shared__ float xr[DIMM];
    xr[k] = x[(size_t)row * DIMM + k];
    __syncthreads();
    const float4* wi  = (const float4*)(Wi + (size_t)k * DIMM);
    const float4* xr4 = (const float4*)xr;
    float acc = bi[k];
#pragma unroll 8
    for (int m = 0; m < DIMM / 4; ++m) {
        float4 w = wi[m]; float4 xv = xr4[m];
        acc += w.x * xv.x + w.y * xv.y + w.z * xv.z + w.w * xv.w;
    }
    xh[(size_t)row * DIMM + k] = acc;
}

// u[b,j,i,e] = sum_d W[j,i,e,d]*xh[b,j,d] + bias[j,i,e]; iter-0 (uniform c)
// partials accumulate straight into s0 via device atomics (32 adders/address).
// xh read with wave-uniform addresses -> scalar loads, no LDS, no barriers.
// grid: (jg, i) = 32*32 = 1024 blocks; thread = e.
__global__ void k_uhat(const float* __restrict__ W, const float* __restrict__ bias,
                       const float* __restrict__ xh, float* __restrict__ u,
                       float* __restrict__ s0) {
    int jg = blockIdx.x >> 5;
    int i  = blockIdx.x & 31;
    int e  = threadIdx.x;
    float acc0[BB];
#pragma unroll
    for (int b = 0; b < BB; ++b) acc0[b] = 0.f;

    for (int jj = 0; jj < JPU; ++jj) {
        int j = jg * JPU + jj;
        const float4* wp = (const float4*)(W + (((size_t)j * NW + i) * NI + e) * DH);
        float4 w4[8];
#pragma unroll
        for (int q = 0; q < 8; ++q) w4[q] = wp[q];
        const float* w = (const float*)w4;
        float bv = bias[((size_t)j * NW + i) * NI + e];
        float* up = u + ((size_t)j * NW + i) * NI + e;
#pragma unroll
        for (int b = 0; b < BB; ++b) {
            const float* xb = xh + ((size_t)b * NJ + j) * DH;   // uniform address
            float a = bv;
#pragma unroll
            for (int d = 0; d < DH; ++d) a += w[d] * xb[d];
            up[(size_t)b * NJ * NW * NI] = a;
            acc0[b] += a;
        }
    }
#pragma unroll
    for (int b = 0; b < BB; ++b)
        atomicAdd(&s0[((size_t)b * NW + i) * NI + e], acc0[b]);
}

// One routing iteration over this block's JPR j's.
// Prologue: v = squash(vscale * s_in) computed in registers (per 8-lane group).
// Body: per j: 32-FMA partial dot, 3-step shfl_xor reduce, beta via LDS,
// 8-lane-group parallel softmax, accumulate c*u in regs.
// Epilogue: atomicAdd the block's partial s into s_out (32 adders/address).
// grid: (b, jg) = 16*32 = 512 blocks (exactly 2/CU) -> launch_bounds(256,2)
// keeps the 256-VGPR cap: vr/ur/s_acc MUST stay in registers (round-2 lesson).
__global__ void __launch_bounds__(256, 2)
k_route(const float* __restrict__ u, const float* __restrict__ s_in,
        float* __restrict__ b_log, float* __restrict__ s_out,
        float vscale, int accflag) {
    int b  = blockIdx.x >> 5;
    int jg = blockIdx.x & 31;
    int t  = threadIdx.x;
    int i  = t >> 3;
    int h  = t & 7;
    __shared__ float sm[NW];

    // ---- squash prologue: vr = squash(vscale * s_in[b,i,:])[h*32 ..] ----
    float vr[32];
    {
        const float4* sp = (const float4*)(s_in + ((size_t)b * NW + i) * NI + h * 32);
#pragma unroll
        for (int q = 0; q < 8; ++q) ((float4*)vr)[q] = sp[q];
    }
    float n2p = 0.f;
#pragma unroll
    for (int k = 0; k < 32; ++k) n2p += vr[k] * vr[k];
    n2p += __shfl_xor(n2p, 1);
    n2p += __shfl_xor(n2p, 2);
    n2p += __shfl_xor(n2p, 4);
    float n2 = vscale * vscale * n2p;          // |s|^2 with s = vscale*s_raw
    float n  = sqrtf(n2);
    float f  = n / (1.0f + n2) * vscale;       // v = f_ref * vscale * s_raw
#pragma unroll
    for (int k = 0; k < 32; ++k) vr[k] *= f;

    float s_acc[32];
#pragma unroll
    for (int k = 0; k < 32; ++k) s_acc[k] = 0.f;

    for (int jj = 0; jj < JPR; ++jj) {
        int j = jg * JPR + jj;
        float ur[32];
        {
            const float4* up = (const float4*)(u + (((size_t)b * NJ + j) * NW + i) * NI + h * 32);
#pragma unroll
            for (int q = 0; q < 8; ++q) ((float4*)ur)[q] = up[q];
        }
        float p = 0.f;
#pragma unroll
        for (int k = 0; k < 32; ++k) p += ur[k] * vr[k];
        p += __shfl_xor(p, 1);
        p += __shfl_xor(p, 2);
        p += __shfl_xor(p, 4);
        __syncthreads();             // previous jj's sm readers are done
        if (h == 0) {
            size_t bidx = ((size_t)b * NJ + j) * NW + i;
            float bta = p;
            if (accflag) bta += b_log[bidx];
            b_log[bidx] = bta;
            sm[i] = bta;
        }
        __syncthreads();
        // 8-lane-group parallel softmax over the 32 output capsules
        float r0 = sm[h * 4 + 0];
        float r1 = sm[h * 4 + 1];
        float r2 = sm[h * 4 + 2];
        float r3 = sm[h * 4 + 3];
        float m = fmaxf(fmaxf(r0, r1), fmaxf(r2, r3));
        m = fmaxf(m, __shfl_xor(m, 1));
        m = fmaxf(m, __shfl_xor(m, 2));
        m = fmaxf(m, __shfl_xor(m, 4));
        float ss = __expf(r0 - m) + __expf(r1 - m) + __expf(r2 - m) + __expf(r3 - m);
        ss += __shfl_xor(ss, 1);
        ss += __shfl_xor(ss, 2);
        ss += __shfl_xor(ss, 4);
        float c = __expf(sm[i] - m) / ss;
#pragma unroll
        for (int k = 0; k < 32; ++k) s_acc[k] += c * ur[k];
    }
    // accumulate into global s (complete at next kernel boundary)
    float* so = s_out + ((size_t)b * NW + i) * NI + h * 32;
#pragma unroll
    for (int k = 0; k < 32; ++k) atomicAdd(&so[k], s_acc[k]);
}

// out = squash(s2) @ Wo^T + bo   (squash folded into the projection head)
// grid: (b,i) = 512 blocks; thread = e / output col.
__global__ void k_proj_out(const float* __restrict__ s2, const float* __restrict__ Wo,
                           const float* __restrict__ bo, float* __restrict__ out) {
    int row = blockIdx.x;          // b*NW + i
    int k = threadIdx.x;
    int lane = k & 63, wave = k >> 6;
    __shared__ float vrow[NI];
    __shared__ float red[4];
    float sv = s2[(size_t)row * NI + k];
    float p = sv * sv;
#pragma unroll
    for (int off = 32; off >= 1; off >>= 1) p += __shfl_down(p, off);
    if (lane == 0) red[wave] = p;
    __syncthreads();
    float n2 = red[0] + red[1] + red[2] + red[3];
    float n = sqrtf(n2);
    float f = n / (1.0f + n2);
    vrow[k] = f * sv;
    __syncthreads();
    const float4* wo  = (const float4*)(Wo + (size_t)k * NI);
    const float4* vr4 = (const float4*)vrow;
    float acc = bo[k];
#pragma unroll 8
    for (int m = 0; m < NI / 4; ++m) {
        float4 w = wo[m]; float4 xv = vr4[m];
        acc += w.x * xv.x + w.y * xv.y + w.z * xv.z + w.w * xv.w;
    }
    out[(size_t)row * DIMM + k] = acc;
}

extern "C" void kernel_launch(void* const* d_in, const int* in_sizes, int n_in,
                              void* d_out, int out_size, void* d_ws, size_t ws_size,
                              hipStream_t stream) {
    const float* x    = (const float*)d_in[0];
    const float* W    = (const float*)d_in[1];
    const float* bias = (const float*)d_in[2];
    const float* Wi   = (const float*)d_in[3];
    const float* bi   = (const float*)d_in[4];
    const float* Wo   = (const float*)d_in[5];
    const float* bo   = (const float*)d_in[6];
    float* out = (float*)d_out;

    float* ws    = (float*)d_ws;
    float* xh    = ws;                      // 131072 floats
    float* u     = ws + 131072;             // 33554432 floats (134 MB)
    float* b_log = u + 33554432;            // 131072 floats
    float* s0    = b_log + 131072;          // 131072 floats (512 KB)
    float* s1    = s0 + 131072;             // 131072
    float* s2    = s1 + 131072;             // 131072

    // P0: inner projection + zero the atomic accumulators
    k_proj_in<<<dim3(BB * NW), dim3(256), 0, stream>>>(x, Wi, bi, xh, s0, s1, s2);
    // P1: u_hat + iter-0 uniform partials -> s0 (atomic)
    k_uhat<<<dim3(JGU * NW), dim3(256), 0, stream>>>(W, bias, xh, u, s0);
    // P2: iter 1 (v0 = squash(s0/NW) in prologue) -> s1 (atomic)
    k_route<<<dim3(BB * JGR), dim3(256), 0, stream>>>(u, s0, b_log, s1, 1.0f / NW, 0);
    // P3: iter 2 (v1 = squash(s1) in prologue) -> s2 (atomic)
    k_route<<<dim3(BB * JGR), dim3(256), 0, stream>>>(u, s1, b_log, s2, 1.0f, 1);
    // P4: out = squash(s2) @ Wo^T + bo
    k_proj_out<<<dim3(BB * NW), dim3(256), 0, stream>>>(s2, Wo, bo, out);
}

// Round 4
// 653.617 us; speedup vs baseline: 2.3539x; 1.3677x over previous
//
#include <hip/hip_runtime.h>

#define BB   16    // batch
#define NW   32    // WORDS (output capsules)
#define DIMM 256   // DIM
#define DH   32    // DIM_HEAD
#define NI   256   // INNER
#define NJ   256   // J = WORDS*HEADS (input capsules)
#define JP   4     // j's per route/uhat block
#define JG   (NJ / JP)   // 64 j-groups

// ---- helpers over NAMED float4s (keeps everything in VGPRs; no pointer puns) ----
#define F4DOT(a, b) ((a).x*(b).x + (a).y*(b).y + (a).z*(b).z + (a).w*(b).w)
#define F4FMA(s, c, a) { (s).x += (c)*(a).x; (s).y += (c)*(a).y; (s).z += (c)*(a).z; (s).w += (c)*(a).w; }

// xi = x @ Wi^T + bi  -> stored as xh [B, NJ, DH] (identical flat layout)
__global__ void k_proj_in(const float* __restrict__ x, const float* __restrict__ Wi,
                          const float* __restrict__ bi, float* __restrict__ xh) {
    int row = blockIdx.x;          // b*NW + n  (512 rows)
    int k = threadIdx.x;           // 0..255
    __shared__ float xr[DIMM];
    xr[k] = x[(size_t)row * DIMM + k];
    __syncthreads();
    const float4* wi  = (const float4*)(Wi + (size_t)k * DIMM);
    const float4* xr4 = (const float4*)xr;
    float acc = bi[k];
#pragma unroll 8
    for (int m = 0; m < DIMM / 4; ++m) {
        float4 w = wi[m]; float4 xv = xr4[m];
        acc += w.x * xv.x + w.y * xv.y + w.z * xv.z + w.w * xv.w;
    }
    xh[(size_t)row * DIMM + k] = acc;
}

// u[b,j,i,e] = sum_d W[j,i,e,d]*xh[b,j,d] + bias[j,i,e]; also writes the
// iter-0 (uniform c) partial sums over this block's JP j's into part.
// W row held in NAMED float4 registers w0..w7 (round-3 lesson: (float*)w4
// punning sent it to scratch -> ~200cy per access, VALUBusy 1.3%).
// xh read with wave-uniform addresses -> scalar K$ loads.
// grid: (jg, i) = 64*32 = 2048 blocks; thread = e.
__global__ void __launch_bounds__(256, 6)
k_uhat(const float* __restrict__ W, const float* __restrict__ bias,
       const float* __restrict__ xh, float* __restrict__ u,
       float* __restrict__ part) {
    int jg = blockIdx.x >> 5;
    int i  = blockIdx.x & 31;
    int e  = threadIdx.x;
    float acc0[BB];
#pragma unroll
    for (int b = 0; b < BB; ++b) acc0[b] = 0.f;

    for (int jj = 0; jj < JP; ++jj) {
        int j = jg * JP + jj;
        const float4* wp = (const float4*)(W + (((size_t)j * NW + i) * NI + e) * DH);
        float4 w0 = wp[0], w1 = wp[1], w2 = wp[2], w3 = wp[3];
        float4 w4 = wp[4], w5 = wp[5], w6 = wp[6], w7 = wp[7];
        float bv = bias[((size_t)j * NW + i) * NI + e];
        float* up = u + ((size_t)j * NW + i) * NI + e;
#pragma unroll
        for (int b = 0; b < BB; ++b) {
            const float* xb = xh + ((size_t)b * NJ + j) * DH;   // wave-uniform
            float a = bv;
            a += w0.x*xb[ 0] + w0.y*xb[ 1] + w0.z*xb[ 2] + w0.w*xb[ 3];
            a += w1.x*xb[ 4] + w1.y*xb[ 5] + w1.z*xb[ 6] + w1.w*xb[ 7];
            a += w2.x*xb[ 8] + w2.y*xb[ 9] + w2.z*xb[10] + w2.w*xb[11];
            a += w3.x*xb[12] + w3.y*xb[13] + w3.z*xb[14] + w3.w*xb[15];
            a += w4.x*xb[16] + w4.y*xb[17] + w4.z*xb[18] + w4.w*xb[19];
            a += w5.x*xb[20] + w5.y*xb[21] + w5.z*xb[22] + w5.w*xb[23];
            a += w6.x*xb[24] + w6.y*xb[25] + w6.z*xb[26] + w6.w*xb[27];
            a += w7.x*xb[28] + w7.y*xb[29] + w7.z*xb[30] + w7.w*xb[31];
            up[(size_t)b * NJ * NW * NI] = a;
            acc0[b] += a;
        }
    }
#pragma unroll
    for (int b = 0; b < BB; ++b)
        part[(((size_t)b * JG + jg) * NW + i) * NI + e] = acc0[b];
}

// One routing iteration over this block's JP j's.
// Thread mapping: t -> i = t>>3 (0..31), h = t&7, e-slice = h*32 .. h*32+31.
// All per-thread 32-float tiles live in NAMED float4s -> VGPR-resident.
// grid: (b, jg) = 16*64 = 1024 blocks (4/CU); launch_bounds(256,4) caps
// VGPR at 128 (demand ~110) so all 4 blocks/CU stay resident.
__global__ void __launch_bounds__(256, 4)
k_route(const float* __restrict__ u, const float* __restrict__ v,
        float* __restrict__ b_log, float* __restrict__ part, int accflag) {
    int b  = blockIdx.x / JG;
    int jg = blockIdx.x % JG;
    int t  = threadIdx.x;
    int i  = t >> 3;
    int h  = t & 7;
    __shared__ float sm[NW];

    // v fragment: v[b, i, h*32 .. h*32+31]
    const float4* vp = (const float4*)(v + ((size_t)b * NW + i) * NI + h * 32);
    float4 v0 = vp[0], v1 = vp[1], v2 = vp[2], v3 = vp[3];
    float4 v4 = vp[4], v5 = vp[5], v6 = vp[6], v7 = vp[7];

    float4 s0 = {0,0,0,0}, s1 = {0,0,0,0}, s2 = {0,0,0,0}, s3 = {0,0,0,0};
    float4 s4 = {0,0,0,0}, s5 = {0,0,0,0}, s6 = {0,0,0,0}, s7 = {0,0,0,0};

    for (int jj = 0; jj < JP; ++jj) {
        int j = jg * JP + jj;
        const float4* up = (const float4*)(u + (((size_t)b * NJ + j) * NW + i) * NI + h * 32);
        float4 u0 = up[0], u1 = up[1], u2 = up[2], u3 = up[3];
        float4 u4 = up[4], u5 = up[5], u6 = up[6], u7 = up[7];

        float p = F4DOT(u0, v0) + F4DOT(u1, v1) + F4DOT(u2, v2) + F4DOT(u3, v3)
                + F4DOT(u4, v4) + F4DOT(u5, v5) + F4DOT(u6, v6) + F4DOT(u7, v7);
        p += __shfl_xor(p, 1);
        p += __shfl_xor(p, 2);
        p += __shfl_xor(p, 4);
        __syncthreads();             // previous jj's sm readers are done
        if (h == 0) {
            size_t bidx = ((size_t)b * NJ + j) * NW + i;
            float bta = p;
            if (accflag) bta += b_log[bidx];
            b_log[bidx] = bta;
            sm[i] = bta;
        }
        __syncthreads();
        // 8-lane-group parallel softmax over the 32 output capsules
        float r0 = sm[h * 4 + 0];
        float r1 = sm[h * 4 + 1];
        float r2 = sm[h * 4 + 2];
        float r3 = sm[h * 4 + 3];
        float m = fmaxf(fmaxf(r0, r1), fmaxf(r2, r3));
        m = fmaxf(m, __shfl_xor(m, 1));
        m = fmaxf(m, __shfl_xor(m, 2));
        m = fmaxf(m, __shfl_xor(m, 4));
        float ss = __expf(r0 - m) + __expf(r1 - m) + __expf(r2 - m) + __expf(r3 - m);
        ss += __shfl_xor(ss, 1);
        ss += __shfl_xor(ss, 2);
        ss += __shfl_xor(ss, 4);
        float c = __expf(sm[i] - m) / ss;
        F4FMA(s0, c, u0); F4FMA(s1, c, u1); F4FMA(s2, c, u2); F4FMA(s3, c, u3);
        F4FMA(s4, c, u4); F4FMA(s5, c, u5); F4FMA(s6, c, u6); F4FMA(s7, c, u7);
    }
    // write split-k partial: part[b, jg, i, h*32 ..]
    float4* pp = (float4*)(part + (((size_t)b * JG + jg) * NW + i) * NI + h * 32);
    pp[0] = s0; pp[1] = s1; pp[2] = s2; pp[3] = s3;
    pp[4] = s4; pp[5] = s5; pp[6] = s6; pp[7] = s7;
}

// s[b,i,e] = scale * sum_g part[b,g,i,e];  v = squash(s)
// grid: (b,i) = 512 blocks; thread = e.
__global__ void k_reduce(const float* __restrict__ part, float* __restrict__ v,
                         float scale) {
    int b = blockIdx.x >> 5;
    int i = blockIdx.x & 31;
    int tid = threadIdx.x;
    int lane = tid & 63, wave = tid >> 6;
    float acc = 0.f;
#pragma unroll 16
    for (int g = 0; g < JG; ++g)
        acc += part[(((size_t)b * JG + g) * NW + i) * NI + tid];
    acc *= scale;
    __shared__ float red[4];
    float p = acc * acc;
#pragma unroll
    for (int off = 32; off >= 1; off >>= 1) p += __shfl_down(p, off);
    if (lane == 0) red[wave] = p;
    __syncthreads();
    float n2 = red[0] + red[1] + red[2] + red[3];
    float n = sqrtf(n2);
    float f = n / (1.0f + n2);
    v[((size_t)b * NW + i) * NI + tid] = f * acc;
}

// out = v @ Wo^T + bo
__global__ void k_proj_out(const float* __restrict__ v, const float* __restrict__ Wo,
                           const float* __restrict__ bo, float* __restrict__ out) {
    int row = blockIdx.x;          // b*NW + i
    int k = threadIdx.x;
    __shared__ float vr[NI];
    vr[k] = v[(size_t)row * NI + k];
    __syncthreads();
    const float4* wo  = (const float4*)(Wo + (size_t)k * NI);
    const float4* vr4 = (const float4*)vr;
    float acc = bo[k];
#pragma unroll 8
    for (int m = 0; m < NI / 4; ++m) {
        float4 w = wo[m]; float4 xv = vr4[m];
        acc += w.x * xv.x + w.y * xv.y + w.z * xv.z + w.w * xv.w;
    }
    out[(size_t)row * DIMM + k] = acc;
}

extern "C" void kernel_launch(void* const* d_in, const int* in_sizes, int n_in,
                              void* d_out, int out_size, void* d_ws, size_t ws_size,
                              hipStream_t stream) {
    const float* x    = (const float*)d_in[0];
    const float* W    = (const float*)d_in[1];
    const float* bias = (const float*)d_in[2];
    const float* Wi   = (const float*)d_in[3];
    const float* bi   = (const float*)d_in[4];
    const float* Wo   = (const float*)d_in[5];
    const float* bo   = (const float*)d_in[6];
    float* out = (float*)d_out;

    float* ws    = (float*)d_ws;
    float* xh    = ws;                      // 131072 floats
    float* u     = ws + 131072;             // 33554432 floats (134 MB)
    float* part  = u + 33554432;            // 8388608 floats (32 MB)
    float* b_log = part + 8388608;          // 131072
    float* v     = b_log + 131072;          // 131072

    k_proj_in<<<dim3(BB * NW), dim3(256), 0, stream>>>(x, Wi, bi, xh);
    // u_hat + iter-0 uniform partial sums
    k_uhat<<<dim3(JG * NW), dim3(256), 0, stream>>>(W, bias, xh, u, part);
    k_reduce<<<dim3(BB * NW), dim3(256), 0, stream>>>(part, v, 1.0f / NW);  // v0
    // iter 1
    k_route<<<dim3(BB * JG), dim3(256), 0, stream>>>(u, v, b_log, part, 0);
    k_reduce<<<dim3(BB * NW), dim3(256), 0, stream>>>(part, v, 1.0f);       // v1
    // iter 2
    k_route<<<dim3(BB * JG), dim3(256), 0, stream>>>(u, v, b_log, part, 1);
    k_reduce<<<dim3(BB * NW), dim3(256), 0, stream>>>(part, v, 1.0f);       // v2
    k_proj_out<<<dim3(BB * NW), dim3(256), 0, stream>>>(v, Wo, bo, out);
}

// Round 5
// 552.871 us; speedup vs baseline: 2.7829x; 1.1822x over previous
//
#include <hip/hip_runtime.h>

#define BB   16    // batch
#define NW   32    // WORDS (output capsules)
#define DIMM 256   // DIM
#define DH   32    // DIM_HEAD
#define NI   256   // INNER
#define NJ   256   // J = WORDS*HEADS (input capsules)
#define JP   4     // j's per route/uhat block
#define JG   (NJ / JP)   // 64 j-groups

// ---- helpers over NAMED float4s (keeps everything in VGPRs; no pointer puns) ----
#define F4DOT(a, b) ((a).x*(b).x + (a).y*(b).y + (a).z*(b).z + (a).w*(b).w)
#define F4FMA(s, c, a) { (s).x += (c)*(a).x; (s).y += (c)*(a).y; (s).z += (c)*(a).z; (s).w += (c)*(a).w; }

// xi = x @ Wi^T + bi  -> stored as xh [B, NJ, DH] (identical flat layout)
__global__ void k_proj_in(const float* __restrict__ x, const float* __restrict__ Wi,
                          const float* __restrict__ bi, float* __restrict__ xh) {
    int row = blockIdx.x;          // b*NW + n  (512 rows)
    int k = threadIdx.x;           // 0..255
    __shared__ float xr[DIMM];
    xr[k] = x[(size_t)row * DIMM + k];
    __syncthreads();
    const float4* wi  = (const float4*)(Wi + (size_t)k * DIMM);
    const float4* xr4 = (const float4*)xr;
    float acc = bi[k];
#pragma unroll 8
    for (int m = 0; m < DIMM / 4; ++m) {
        float4 w = wi[m]; float4 xv = xr4[m];
        acc += w.x * xv.x + w.y * xv.y + w.z * xv.z + w.w * xv.w;
    }
    xh[(size_t)row * DIMM + k] = acc;
}

// u[b,j,i,e] = sum_d W[j,i,e,d]*xh[b,j,d] + bias[j,i,e].
// PURE STREAMING: no per-thread arrays at all (round-4 lesson: acc0[16]
// alloca demoted the frame to scratch -> VGPR=40, +300MB write-back).
// Iter-0 partial sums were removed; k_reduce now sums u directly for v0.
// W row in NAMED float4s; xh via wave-uniform scalar loads (SGPRs).
// grid: (jg, i) = 64*32 = 2048 blocks; thread = e.
__global__ void __launch_bounds__(256, 4)
k_uhat(const float* __restrict__ W, const float* __restrict__ bias,
       const float* __restrict__ xh, float* __restrict__ u) {
    int jg = blockIdx.x >> 5;
    int i  = blockIdx.x & 31;
    int e  = threadIdx.x;

    for (int jj = 0; jj < JP; ++jj) {
        int j = jg * JP + jj;
        const float4* wp = (const float4*)(W + (((size_t)j * NW + i) * NI + e) * DH);
        float4 w0 = wp[0], w1 = wp[1], w2 = wp[2], w3 = wp[3];
        float4 w4 = wp[4], w5 = wp[5], w6 = wp[6], w7 = wp[7];
        float bv = bias[((size_t)j * NW + i) * NI + e];
        float* up = u + ((size_t)j * NW + i) * NI + e;
        const float* xb0 = xh + (size_t)j * DH;
#pragma unroll 4
        for (int b = 0; b < BB; ++b) {
            const float* xb = xb0 + (size_t)b * NJ * DH;   // wave-uniform
            float a = bv;
            a += w0.x*xb[ 0] + w0.y*xb[ 1] + w0.z*xb[ 2] + w0.w*xb[ 3];
            a += w1.x*xb[ 4] + w1.y*xb[ 5] + w1.z*xb[ 6] + w1.w*xb[ 7];
            a += w2.x*xb[ 8] + w2.y*xb[ 9] + w2.z*xb[10] + w2.w*xb[11];
            a += w3.x*xb[12] + w3.y*xb[13] + w3.z*xb[14] + w3.w*xb[15];
            a += w4.x*xb[16] + w4.y*xb[17] + w4.z*xb[18] + w4.w*xb[19];
            a += w5.x*xb[20] + w5.y*xb[21] + w5.z*xb[22] + w5.w*xb[23];
            a += w6.x*xb[24] + w6.y*xb[25] + w6.z*xb[26] + w6.w*xb[27];
            a += w7.x*xb[28] + w7.y*xb[29] + w7.z*xb[30] + w7.w*xb[31];
            up[(size_t)b * NJ * NW * NI] = a;
        }
    }
}

// One routing iteration over this block's JP j's (unchanged from round 4 —
// it codegens cleanly: named float4s, lb(256,4)).
__global__ void __launch_bounds__(256, 4)
k_route(const float* __restrict__ u, const float* __restrict__ v,
        float* __restrict__ b_log, float* __restrict__ part, int accflag) {
    int b  = blockIdx.x / JG;
    int jg = blockIdx.x % JG;
    int t  = threadIdx.x;
    int i  = t >> 3;
    int h  = t & 7;
    __shared__ float sm[NW];

    const float4* vp = (const float4*)(v + ((size_t)b * NW + i) * NI + h * 32);
    float4 v0 = vp[0], v1 = vp[1], v2 = vp[2], v3 = vp[3];
    float4 v4 = vp[4], v5 = vp[5], v6 = vp[6], v7 = vp[7];

    float4 s0 = {0,0,0,0}, s1 = {0,0,0,0}, s2 = {0,0,0,0}, s3 = {0,0,0,0};
    float4 s4 = {0,0,0,0}, s5 = {0,0,0,0}, s6 = {0,0,0,0}, s7 = {0,0,0,0};

    for (int jj = 0; jj < JP; ++jj) {
        int j = jg * JP + jj;
        const float4* up = (const float4*)(u + (((size_t)b * NJ + j) * NW + i) * NI + h * 32);
        float4 u0 = up[0], u1 = up[1], u2 = up[2], u3 = up[3];
        float4 u4 = up[4], u5 = up[5], u6 = up[6], u7 = up[7];

        float p = F4DOT(u0, v0) + F4DOT(u1, v1) + F4DOT(u2, v2) + F4DOT(u3, v3)
                + F4DOT(u4, v4) + F4DOT(u5, v5) + F4DOT(u6, v6) + F4DOT(u7, v7);
        p += __shfl_xor(p, 1);
        p += __shfl_xor(p, 2);
        p += __shfl_xor(p, 4);
        __syncthreads();             // previous jj's sm readers are done
        if (h == 0) {
            size_t bidx = ((size_t)b * NJ + j) * NW + i;
            float bta = p;
            if (accflag) bta += b_log[bidx];
            b_log[bidx] = bta;
            sm[i] = bta;
        }
        __syncthreads();
        // 8-lane-group parallel softmax over the 32 output capsules
        float r0 = sm[h * 4 + 0];
        float r1 = sm[h * 4 + 1];
        float r2 = sm[h * 4 + 2];
        float r3 = sm[h * 4 + 3];
        float m = fmaxf(fmaxf(r0, r1), fmaxf(r2, r3));
        m = fmaxf(m, __shfl_xor(m, 1));
        m = fmaxf(m, __shfl_xor(m, 2));
        m = fmaxf(m, __shfl_xor(m, 4));
        float ss = __expf(r0 - m) + __expf(r1 - m) + __expf(r2 - m) + __expf(r3 - m);
        ss += __shfl_xor(ss, 1);
        ss += __shfl_xor(ss, 2);
        ss += __shfl_xor(ss, 4);
        float c = __expf(sm[i] - m) / ss;
        F4FMA(s0, c, u0); F4FMA(s1, c, u1); F4FMA(s2, c, u2); F4FMA(s3, c, u3);
        F4FMA(s4, c, u4); F4FMA(s5, c, u5); F4FMA(s6, c, u6); F4FMA(s7, c, u7);
    }
    float4* pp = (float4*)(part + (((size_t)b * JG + jg) * NW + i) * NI + h * 32);
    pp[0] = s0; pp[1] = s1; pp[2] = s2; pp[3] = s3;
    pp[4] = s4; pp[5] = s5; pp[6] = s6; pp[7] = s7;
}

// s[b,i,e] = scale * sum_g src[b,g,i,e] over NG groups;  v = squash(s).
// NG=NJ(256) reading u directly (v0, replaces uhat's acc0/part path);
// NG=JG(64) reading part (v1, v2).
// grid: (b,i) = 512 blocks; thread = e.
__global__ void k_reduce(const float* __restrict__ src, float* __restrict__ v,
                         float scale, int NG) {
    int b = blockIdx.x >> 5;
    int i = blockIdx.x & 31;
    int tid = threadIdx.x;
    int lane = tid & 63, wave = tid >> 6;
    float acc = 0.f;
#pragma unroll 8
    for (int g = 0; g < NG; ++g)
        acc += src[(((size_t)b * NG + g) * NW + i) * NI + tid];
    acc *= scale;
    __shared__ float red[4];
    float p = acc * acc;
#pragma unroll
    for (int off = 32; off >= 1; off >>= 1) p += __shfl_down(p, off);
    if (lane == 0) red[wave] = p;
    __syncthreads();
    float n2 = red[0] + red[1] + red[2] + red[3];
    float n = sqrtf(n2);
    float f = n / (1.0f + n2);
    v[((size_t)b * NW + i) * NI + tid] = f * acc;
}

// out = v @ Wo^T + bo
__global__ void k_proj_out(const float* __restrict__ v, const float* __restrict__ Wo,
                           const float* __restrict__ bo, float* __restrict__ out) {
    int row = blockIdx.x;          // b*NW + i
    int k = threadIdx.x;
    __shared__ float vr[NI];
    vr[k] = v[(size_t)row * NI + k];
    __syncthreads();
    const float4* wo  = (const float4*)(Wo + (size_t)k * NI);
    const float4* vr4 = (const float4*)vr;
    float acc = bo[k];
#pragma unroll 8
    for (int m = 0; m < NI / 4; ++m) {
        float4 w = wo[m]; float4 xv = vr4[m];
        acc += w.x * xv.x + w.y * xv.y + w.z * xv.z + w.w * xv.w;
    }
    out[(size_t)row * DIMM + k] = acc;
}

extern "C" void kernel_launch(void* const* d_in, const int* in_sizes, int n_in,
                              void* d_out, int out_size, void* d_ws, size_t ws_size,
                              hipStream_t stream) {
    const float* x    = (const float*)d_in[0];
    const float* W    = (const float*)d_in[1];
    const float* bias = (const float*)d_in[2];
    const float* Wi   = (const float*)d_in[3];
    const float* bi   = (const float*)d_in[4];
    const float* Wo   = (const float*)d_in[5];
    const float* bo   = (const float*)d_in[6];
    float* out = (float*)d_out;

    float* ws    = (float*)d_ws;
    float* xh    = ws;                      // 131072 floats
    float* u     = ws + 131072;             // 33554432 floats (134 MB)
    float* part  = u + 33554432;            // 8388608 floats (32 MB)
    float* b_log = part + 8388608;          // 131072
    float* v     = b_log + 131072;          // 131072

    k_proj_in<<<dim3(BB * NW), dim3(256), 0, stream>>>(x, Wi, bi, xh);
    // u_hat (pure streaming, no partials)
    k_uhat<<<dim3(JG * NW), dim3(256), 0, stream>>>(W, bias, xh, u);
    // v0 = squash(mean over all 256 j of u)
    k_reduce<<<dim3(BB * NW), dim3(256), 0, stream>>>(u, v, 1.0f / NW, NJ);
    // iter 1
    k_route<<<dim3(BB * JG), dim3(256), 0, stream>>>(u, v, b_log, part, 0);
    k_reduce<<<dim3(BB * NW), dim3(256), 0, stream>>>(part, v, 1.0f, JG);   // v1
    // iter 2
    k_route<<<dim3(BB * JG), dim3(256), 0, stream>>>(u, v, b_log, part, 1);
    k_reduce<<<dim3(BB * NW), dim3(256), 0, stream>>>(part, v, 1.0f, JG);   // v2
    k_proj_out<<<dim3(BB * NW), dim3(256), 0, stream>>>(v, Wo, bo, out);
}